// Round 2
// 616.312 us; speedup vs baseline: 1.1031x; 1.1031x over previous
//
#include <hip/hip_runtime.h>
#include <stdint.h>

// UpsampleUpFIRDn: 2x upsample + 4x4 FIR (upfirdn2d, up=2, down=1, pad0=2, pad1=1)
// x: (8,64,256,256) FP32 -> out: (8,64,512,512) FP32; kernel: 4x4 FP32 (pre-scaled by factor^2)
//
// R1/R2 post-mortems (prev session): input and output are both FP32.
// R3 theory: timed region = ~340us poison fill (fixed) + ~340us kernel. Kernel was at
// ~2 TB/s effective (not BW-bound): 2x read-instruction redundancy + L2 write pollution.
// R4: R3 bench never ran (GPU acquisition timeout) — resubmitting identical kernel.
//
// Parity decomposition (verified analytically vs the flip+dilated-conv reference):
//   output row y: py=y&1, i=y>>1
//     py=0: taps (row i-1, krow 3), (row i, krow 1)
//     py=1: taps (row i,   krow 2), (row i+1, krow 0)
//   same mapping for columns.
//
// Row-pair restructure: output rows 2q+1 (py=1, i=q) and 2q+2 (py=0, i=q+1) both read
// ONLY input rows (q, q+1):
//   y1 = 2q+1 : (row q, krow 2), (row q+1, krow 0)
//   y2 = 2q+2 : (row q, krow 3), (row q+1, krow 1)
// One warp = one pair q in [-1, 255]; q=-1 emits only y=0 (row -1 side zeroed),
// q=255 emits only y=511 (row 256 side zeroed). 16 outputs/thread, 2 row loads/thread.
// Output stores are nontemporal (streaming, no reuse) to keep input rows in L2.

#define IN_H 256
#define IN_W 256
#define OUT_H 512
#define OUT_W 512

typedef float f4 __attribute__((ext_vector_type(4)));

__global__ __launch_bounds__(256) void upfirdn2x_kernel(
    const float* __restrict__ x,    // [nch][256][256]
    const float* __restrict__ k2,   // [4][4]
    float* __restrict__ out)        // [nch][512][512]
{
    const int t  = threadIdx.x & 63;   // 64 threads across the row; 8 output cols each
    const int ty = threadIdx.x >> 6;   // 4 row-pairs per block; wave == one pair (uniform branches)
    const int q  = blockIdx.x * 4 + ty - 1;   // input-row-pair index, -1..255
    if (q >= IN_H) return;                    // tail warps of the last x-block
    const int ch = blockIdx.y;

    const bool vA = (q >= 0);          // row q valid
    const bool vB = (q + 1 < IN_H);    // row q+1 valid

    const float* xc   = x + (size_t)ch * (IN_H * IN_W);
    const float* rowA = xc + (size_t)(vA ? q     : 0) * IN_W;
    const float* rowB = xc + (size_t)(vB ? q + 1 : 0) * IN_W;

    const int c0 = 4 * t;  // input cols c0..c0+3 (16B-aligned)
    const f4 a4 = *reinterpret_cast<const f4*>(rowA + c0);
    const f4 b4 = *reinterpret_cast<const f4*>(rowB + c0);

    // input cols c0-1 .. c0+4, zero-padded at image edges
    float cA[6], cB[6];
    cA[0] = (t > 0)  ? rowA[c0 - 1] : 0.0f;
    cB[0] = (t > 0)  ? rowB[c0 - 1] : 0.0f;
    cA[5] = (t < 63) ? rowA[c0 + 4] : 0.0f;
    cB[5] = (t < 63) ? rowB[c0 + 4] : 0.0f;
    cA[1] = a4.x; cA[2] = a4.y; cA[3] = a4.z; cA[4] = a4.w;
    cB[1] = b4.x; cB[2] = b4.y; cB[3] = b4.z; cB[4] = b4.w;

    if (!vA) {   // wave-uniform, only the q=-1 edge pair
#pragma unroll
        for (int c = 0; c < 6; ++c) cA[c] = 0.0f;
    }
    if (!vB) {   // wave-uniform, only the q=255 edge pair
#pragma unroll
        for (int c = 0; c < 6; ++c) cB[c] = 0.0f;
    }

    // all 16 weights, wave-uniform
    float kw[16];
#pragma unroll
    for (int i = 0; i < 16; ++i) kw[i] = k2[i];

    // y1 = 2q+1 : A-row weights = krow 2 (kw[8..11]),  B-row = krow 0 (kw[0..3])
    // y2 = 2q+2 : A-row weights = krow 3 (kw[12..15]), B-row = krow 1 (kw[4..7])
    float o1[8], o2[8];
#pragma unroll
    for (int u = 0; u < 8; ++u) {
        const int j = u >> 1;
        if ((u & 1) == 0) {
            // px=0: cols (j-1, kcol 3), (j, kcol 1)
            o1[u] = kw[8+3]*cA[j]  + kw[8+1]*cA[j+1]  + kw[0+3]*cB[j]  + kw[0+1]*cB[j+1];
            o2[u] = kw[12+3]*cA[j] + kw[12+1]*cA[j+1] + kw[4+3]*cB[j]  + kw[4+1]*cB[j+1];
        } else {
            // px=1: cols (j, kcol 2), (j+1, kcol 0)
            o1[u] = kw[8+2]*cA[j+1]  + kw[8+0]*cA[j+2]  + kw[0+2]*cB[j+1] + kw[0+0]*cB[j+2];
            o2[u] = kw[12+2]*cA[j+1] + kw[12+0]*cA[j+2] + kw[4+2]*cB[j+1] + kw[4+0]*cB[j+2];
        }
    }

    float* ob = out + (size_t)ch * (OUT_H * OUT_W);
    if (vA) {  // y1 = 2q+1 in [1, 511]
        float* op = ob + (size_t)(2 * q + 1) * OUT_W + 8 * t;
        f4 s0; s0.x = o1[0]; s0.y = o1[1]; s0.z = o1[2]; s0.w = o1[3];
        f4 s1; s1.x = o1[4]; s1.y = o1[5]; s1.z = o1[6]; s1.w = o1[7];
        __builtin_nontemporal_store(s0, reinterpret_cast<f4*>(op));
        __builtin_nontemporal_store(s1, reinterpret_cast<f4*>(op + 4));
    }
    if (vB) {  // y2 = 2q+2 in [0, 510]
        float* op = ob + (size_t)(2 * q + 2) * OUT_W + 8 * t;
        f4 s0; s0.x = o2[0]; s0.y = o2[1]; s0.z = o2[2]; s0.w = o2[3];
        f4 s1; s1.x = o2[4]; s1.y = o2[5]; s1.z = o2[6]; s1.w = o2[7];
        __builtin_nontemporal_store(s0, reinterpret_cast<f4*>(op));
        __builtin_nontemporal_store(s1, reinterpret_cast<f4*>(op + 4));
    }
}

extern "C" void kernel_launch(void* const* d_in, const int* in_sizes, int n_in,
                              void* d_out, int out_size, void* d_ws, size_t ws_size,
                              hipStream_t stream) {
    const float* x  = (const float*)d_in[0];   // fp32, 8*64*256*256
    const float* k2 = (const float*)d_in[1];   // fp32, 16 elems
    float* out = (float*)d_out;                // fp32, 8*64*512*512

    const int nch = in_sizes[0] / (IN_H * IN_W);  // 8*64 = 512
    const int npairs = IN_H + 1;                  // q = -1 .. 255
    dim3 block(256);
    dim3 grid((npairs + 3) / 4, nch);             // 65 x 512
    upfirdn2x_kernel<<<grid, block, 0, stream>>>(x, k2, out);
}